// Round 5
// baseline (199.790 us; speedup 1.0000x reference)
//
#include <hip/hip_runtime.h>
#include <hip/hip_bf16.h>
#include <cstdint>

#define HDIM 1024
#define NT 32   // K-tiles of 32

typedef __attribute__((ext_vector_type(8))) __bf16 bf16x8;
typedef __attribute__((ext_vector_type(8))) unsigned short u16x8;
typedef __attribute__((ext_vector_type(4))) float f32x4;

static __device__ __forceinline__ unsigned short f2b(float f) {
    __hip_bfloat16 h = __float2bfloat16(f);
    return __builtin_bit_cast(unsigned short, h);
}

static __device__ __forceinline__ void barrier_fence() {
    asm volatile("" ::: "memory");
    __builtin_amdgcn_s_barrier();
    asm volatile("" ::: "memory");
}

// ---------------- weights fp32 -> bf16 row-major (12 MB in ws) ----------------
__global__ void __launch_bounds__(256) cvt_w(
    const float* __restrict__ wih, const float* __restrict__ ur,
    const float* __restrict__ uz, const float* __restrict__ un,
    unsigned short* __restrict__ wb, unsigned short* __restrict__ urb,
    unsigned short* __restrict__ uzb, unsigned short* __restrict__ unb) {
    int b = blockIdx.x;
    const float* src; unsigned short* dst; int idx;
    if (b < 3072)       { src = wih; dst = wb;  idx = b; }
    else if (b < 4096)  { src = ur;  dst = urb; idx = b - 3072; }
    else if (b < 5120)  { src = uz;  dst = uzb; idx = b - 4096; }
    else                { src = un;  dst = unb; idx = b - 5120; }
    int i = idx * 256 + threadIdx.x;
    float4 v = ((const float4*)src)[i];
    ushort4 o;
    o.x = f2b(v.x); o.y = f2b(v.y); o.z = f2b(v.z); o.w = f2b(v.w);
    ((ushort4*)dst)[i] = o;
}

// ---------------- x,h fp32 -> bf16 MFMA-A-fragment pack ----------------
// Fragment layout: xf[kt][f][lane][8] (ushort), where frag f covers rows
// f*16..f*16+15; lane l holds row f*16+(l&15), k = kt*32 + (l>>4)*8 + 0..7.
// One block per f-group (16 rows x 1024 cols), LDS transpose.
__global__ void __launch_bounds__(256) pack_xh(
    const float* __restrict__ x, const float* __restrict__ h,
    unsigned short* __restrict__ xf, unsigned short* __restrict__ hf) {
    __shared__ unsigned short lds[16 * 1032];   // +8 pad per row: conflict-free
    const int b = blockIdx.x;
    const float* src = (b < 512) ? x : h;
    unsigned short* dst = (b < 512) ? xf : hf;
    const int f = b & 511;
    const int tid = threadIdx.x;

    // phase 1: coalesced read 16x1024 fp32, cvt, store LDS
#pragma unroll
    for (int rep = 0; rep < 4; ++rep) {
        const int idx  = rep * 256 + tid;      // 0..1023
        const int row  = idx >> 6;             // 0..15
        const int colg = (idx & 63) * 16;
        const float* g = src + (size_t)(f * 16 + row) * HDIM + colg;
        float4 v0 = ((const float4*)g)[0];
        float4 v1 = ((const float4*)g)[1];
        float4 v2 = ((const float4*)g)[2];
        float4 v3 = ((const float4*)g)[3];
        unsigned short* l = lds + row * 1032 + colg;
        l[0]=f2b(v0.x); l[1]=f2b(v0.y); l[2]=f2b(v0.z); l[3]=f2b(v0.w);
        l[4]=f2b(v1.x); l[5]=f2b(v1.y); l[6]=f2b(v1.z); l[7]=f2b(v1.w);
        l[8]=f2b(v2.x); l[9]=f2b(v2.y); l[10]=f2b(v2.z); l[11]=f2b(v2.w);
        l[12]=f2b(v3.x); l[13]=f2b(v3.y); l[14]=f2b(v3.z); l[15]=f2b(v3.w);
    }
    __syncthreads();

    // phase 2: read frag-order from LDS, write coalesced 1KB per (kt, wave)
#pragma unroll
    for (int rep = 0; rep < 8; ++rep) {
        const int idx = rep * 256 + tid;       // 0..2047
        const int kt  = idx >> 6;              // 0..31
        const int l   = idx & 63;
        u16x8 v = *(const u16x8*)(lds + (l & 15) * 1032 + kt * 32 + (l >> 4) * 8);
        *(u16x8*)(dst + ((size_t)(kt * 512 + f) * 64 + l) * 8) = v;
    }
}

// ---------------- main fused GRU kernel ----------------
// BM=128, BN=64, 8 waves (2M x 4N), WM=64, WN=16. Weights-only LDS
// (2 x 24KB dbuf, R2's proven XOR swizzle); x/h A-frags direct from global
// (frag-packed bf16), double-buffered in named register sets.
__global__ void __launch_bounds__(512, 2)
gru8(const float* __restrict__ hg,
     const unsigned short* __restrict__ xf, const unsigned short* __restrict__ hf,
     const unsigned short* __restrict__ wih,
     const unsigned short* __restrict__ ur,
     const unsigned short* __restrict__ uz,
     const unsigned short* __restrict__ un,
     const float* __restrict__ bih, const float* __restrict__ bun,
     float* __restrict__ out) {
    __shared__ __align__(16) unsigned short smem[2][12288];   // 2 x 24 KB

    const int tid  = threadIdx.x;
    const int lane = tid & 63;
    const int wv   = tid >> 6;     // 0..7
    const int mo   = wv >> 2;      // 0..1  (64-row half)
    const int no   = wv & 3;       // 0..3  (16-col quarter)
    const int lr   = lane & 15;
    const int ls   = lane >> 4;

    // XCD swizzle: 1024 blocks = 64 M x 16 N; each XCD gets 2 N-panels
    const int bid  = blockIdx.x;
    const int swz  = (bid & 7) * 128 + (bid >> 3);
    const int m0   = (swz & 63) * 128;
    const int n0   = (swz >> 6) * 64;

    // ---- weight staging: 3 gload_lds per thread per K-step
    const unsigned short* wb6[6] = {
        wih + (size_t)n0 * HDIM,
        wih + (size_t)(HDIM + n0) * HDIM,
        wih + (size_t)(2 * HDIM + n0) * HDIM,
        ur  + (size_t)n0 * HDIM,
        uz  + (size_t)n0 * HDIM,
        un  + (size_t)n0 * HDIM
    };
    const unsigned short* pwp[3];
    int ldst[3];
#pragma unroll
    for (int l = 0; l < 3; ++l) {
        const int id = l * 512 + tid;          // 0..1535 = 6 tiles x 256 chunks
        const int mi = id >> 8;                // wave-uniform
        const int c  = id & 255;               // chunk within tile
        const int r  = c >> 2;                 // row 0..63
        const int sl = (c & 3) ^ ((c >> 3) & 3);   // pre-swizzled source slot
        pwp[l]  = wb6[mi] + (size_t)r * HDIM + sl * 8;
        ldst[l] = mi * 2048 + (wv & 3) * 512;  // wave-uniform LDS dest (ush)
    }

    // ---- A-frag pointers (frag-packed bf16): slab stride 262144 ush per kt
    const int fbx = (m0 >> 4) + mo * 4;
    const unsigned short* pxA = xf + ((size_t)fbx * 64 + lane) * 8;
    const unsigned short* phA = hf + ((size_t)fbx * 64 + lane) * 8;

    f32x4 acc[4][4];   // [gate][mf]
#pragma unroll
    for (int g = 0; g < 4; ++g)
#pragma unroll
        for (int mf = 0; mf < 4; ++mf)
            acc[g][mf] = f32x4{0.f, 0.f, 0.f, 0.f};

    bf16x8 ax0[4], ah0[4], ax1[4], ah1[4];   // named A sets (static indexing)

    auto STAGE_W = [&](unsigned short* nb) {
#pragma unroll
        for (int l = 0; l < 3; ++l) {
            __builtin_amdgcn_global_load_lds(
                (const __attribute__((address_space(1))) void*)pwp[l],
                (__attribute__((address_space(3))) void*)(nb + ldst[l]), 16, 0, 0);
            pwp[l] += 32;
        }
    };
    auto A_LOAD = [&](bf16x8 (&ax)[4], bf16x8 (&ah)[4]) {
#pragma unroll
        for (int mf = 0; mf < 4; ++mf) ax[mf] = *(const bf16x8*)(pxA + mf * 512);
#pragma unroll
        for (int mf = 0; mf < 4; ++mf) ah[mf] = *(const bf16x8*)(phA + mf * 512);
        pxA += 262144; phA += 262144;
    };
    auto COMPUTE = [&](const unsigned short* sb,
                       const bf16x8 (&ax)[4], const bf16x8 (&ah)[4]) {
        const int wrow = no * 16 + lr;
        const int boff = wrow * 32 + ((ls ^ ((wrow >> 1) & 3)) << 3);
#pragma unroll
        for (int mi = 0; mi < 6; ++mi) {
            bf16x8 bq = *(const bf16x8*)(sb + mi * 2048 + boff);
            const int g = (mi == 0 || mi == 3) ? 0 : (mi == 1 || mi == 4) ? 1 : (mi == 2) ? 2 : 3;
            const bf16x8* a = (mi < 3) ? ax : ah;
#pragma unroll
            for (int mf = 0; mf < 4; ++mf)
                acc[g][mf] = __builtin_amdgcn_mfma_f32_16x16x32_bf16(a[mf], bq, acc[g][mf], 0, 0, 0);
        }
    };
    auto WAIT11 = [&]() { asm volatile("s_waitcnt vmcnt(11)" ::: "memory"); };

    // prologue: stage kt=0 (weights -> buf0, A -> set0)
    STAGE_W(&smem[0][0]);
    A_LOAD(ax0, ah0);

#pragma unroll 1
    for (int t = 0; t < NT - 2; t += 2) {
        STAGE_W(&smem[1][0]); A_LOAD(ax1, ah1);   // kt = t+1
        WAIT11(); barrier_fence();
        COMPUTE(&smem[0][0], ax0, ah0);           // kt = t
        barrier_fence();
        STAGE_W(&smem[0][0]); A_LOAD(ax0, ah0);   // kt = t+2
        WAIT11(); barrier_fence();
        COMPUTE(&smem[1][0], ax1, ah1);           // kt = t+1
        barrier_fence();
    }
    STAGE_W(&smem[1][0]); A_LOAD(ax1, ah1);       // kt = 31
    WAIT11(); barrier_fence();
    COMPUTE(&smem[0][0], ax0, ah0);               // kt = 30
    barrier_fence();
    asm volatile("s_waitcnt vmcnt(0) lgkmcnt(0)" ::: "memory");
    __builtin_amdgcn_s_barrier();
    asm volatile("" ::: "memory");
    COMPUTE(&smem[1][0], ax1, ah1);               // kt = 31

    // epilogue (C/D: col=lane&15, row=(lane>>4)*4+reg)
    const int gc = n0 + no * 16 + lr;
    const float br  = bih[gc];
    const float bz  = bih[HDIM + gc];
    const float bnx = bih[2 * HDIM + gc];
    const float bn2 = bun[gc];
#pragma unroll
    for (int mf = 0; mf < 4; ++mf) {
#pragma unroll
        for (int rr = 0; rr < 4; ++rr) {
            const int gr = m0 + mo * 64 + mf * 16 + ls * 4 + rr;
            const float rv = 1.f / (1.f + __expf(-(acc[0][mf][rr] + br)));
            const float zv = 1.f / (1.f + __expf(-(acc[1][mf][rr] + bz)));
            const float nv = tanhf(acc[2][mf][rr] + bnx + rv * (acc[3][mf][rr] + bn2));
            const float hv = hg[(size_t)gr * HDIM + gc];
            out[(size_t)gr * HDIM + gc] = (1.f - zv) * nv + zv * hv;
        }
    }
}

// ---------- fallback (ws too small): R2's proven 4-wave fp32-staging kernel ----------
__global__ void __launch_bounds__(256, 2)
gru_fused_fb(const float* __restrict__ hg,
             const float* __restrict__ xg32, const float* __restrict__ hg32,
             const unsigned short* __restrict__ wih,
             const unsigned short* __restrict__ ur,
             const unsigned short* __restrict__ uz,
             const unsigned short* __restrict__ un,
             const float* __restrict__ bih, const float* __restrict__ bun,
             float* __restrict__ out) {
    __shared__ __align__(16) unsigned short smem[2][20480];
    const int tid  = threadIdx.x;
    const int lane = tid & 63;
    const int wv   = tid >> 6;
    const int wm   = wv >> 1;
    const int wn   = wv & 1;
    const int lr   = lane & 15;
    const int ls   = lane >> 4;
    const int m0   = blockIdx.y * 128;
    const int n0   = blockIdx.x * 64;

    const unsigned short* wb6[6] = {
        wih + (size_t)n0 * HDIM, wih + (size_t)(HDIM + n0) * HDIM,
        wih + (size_t)(2 * HDIM + n0) * HDIM, ur + (size_t)n0 * HDIM,
        uz + (size_t)n0 * HDIM, un + (size_t)n0 * HDIM
    };
    const int wr  = tid >> 2;
    const int wsl = (tid & 3) ^ ((tid >> 3) & 3);

    f32x4 acc[4][4][2];
#pragma unroll
    for (int g = 0; g < 4; ++g)
#pragma unroll
        for (int mf = 0; mf < 4; ++mf)
#pragma unroll
            for (int nf = 0; nf < 2; ++nf)
                acc[g][mf][nf] = f32x4{0.f, 0.f, 0.f, 0.f};

    auto STAGE = [&](int bufi, int kt) {
        const int k0 = kt * 32;
        unsigned short* sb = &smem[bufi][0];
        float4 fx[2][2], fh[2][2];
#pragma unroll
        for (int half = 0; half < 2; ++half) {
            const int c2 = half * 256 + tid;
            const int r2 = c2 >> 2;
            const int sl = c2 & 3;
            const float* gx = xg32 + (size_t)(m0 + r2) * HDIM + k0 + sl * 8;
            const float* gh = hg32 + (size_t)(m0 + r2) * HDIM + k0 + sl * 8;
            fx[half][0] = ((const float4*)gx)[0];
            fx[half][1] = ((const float4*)gx)[1];
            fh[half][0] = ((const float4*)gh)[0];
            fh[half][1] = ((const float4*)gh)[1];
        }
#pragma unroll
        for (int mi = 0; mi < 6; ++mi) {
            const unsigned short* g = wb6[mi] + (size_t)wr * HDIM + k0 + wsl * 8;
            __builtin_amdgcn_global_load_lds(
                (const __attribute__((address_space(1))) void*)g,
                (__attribute__((address_space(3))) void*)(sb + 8192 + mi * 2048 + wv * 512),
                16, 0, 0);
        }
#pragma unroll
        for (int half = 0; half < 2; ++half) {
            const int c2 = half * 256 + tid;
            const int r2 = c2 >> 2;
            const int sp = (c2 & 3) ^ ((c2 >> 3) & 3);
            u16x8 px, ph;
#pragma unroll
            for (int q = 0; q < 4; ++q) {
                px[q]     = f2b(fx[half][0][q]);
                px[q + 4] = f2b(fx[half][1][q]);
                ph[q]     = f2b(fh[half][0][q]);
                ph[q + 4] = f2b(fh[half][1][q]);
            }
            *(u16x8*)(sb + r2 * 32 + sp * 8)        = px;
            *(u16x8*)(sb + 4096 + r2 * 32 + sp * 8) = ph;
        }
    };
    auto COMPUTE = [&](int bufi) {
        const unsigned short* sb = &smem[bufi][0];
        const int sel = (lr >> 1) & 3;
        const int fo  = (ls ^ sel) << 3;
        bf16x8 ax[4], ah[4];
#pragma unroll
        for (int mf = 0; mf < 4; ++mf) {
            const int row = wm * 64 + mf * 16 + lr;
            ax[mf] = *(const bf16x8*)(sb + row * 32 + fo);
            ah[mf] = *(const bf16x8*)(sb + 4096 + row * 32 + fo);
        }
#pragma unroll
        for (int mi = 0; mi < 6; ++mi) {
            const unsigned short* wt = sb + 8192 + mi * 2048;
            bf16x8 b0 = *(const bf16x8*)(wt + (wn * 32 + lr) * 32 + fo);
            bf16x8 b1 = *(const bf16x8*)(wt + (wn * 32 + 16 + lr) * 32 + fo);
            const int g = (mi == 0 || mi == 3) ? 0 : (mi == 1 || mi == 4) ? 1 : (mi == 2) ? 2 : 3;
            const bf16x8* a = (mi < 3) ? ax : ah;
#pragma unroll
            for (int mf = 0; mf < 4; ++mf) {
                acc[g][mf][0] = __builtin_amdgcn_mfma_f32_16x16x32_bf16(a[mf], b0, acc[g][mf][0], 0, 0, 0);
                acc[g][mf][1] = __builtin_amdgcn_mfma_f32_16x16x32_bf16(a[mf], b1, acc[g][mf][1], 0, 0, 0);
            }
        }
    };
    auto WAITN = [&]() { asm volatile("s_waitcnt vmcnt(6) lgkmcnt(0)" ::: "memory"); };

    STAGE(0, 0);
#pragma unroll 1
    for (int kt = 0; kt < NT - 2; kt += 2) {
        STAGE(1, kt + 1); WAITN(); barrier_fence();
        COMPUTE(0);       barrier_fence();
        STAGE(0, kt + 2); WAITN(); barrier_fence();
        COMPUTE(1);       barrier_fence();
    }
    STAGE(1, NT - 1); WAITN(); barrier_fence();
    COMPUTE(0);       barrier_fence();
    asm volatile("s_waitcnt vmcnt(0) lgkmcnt(0)" ::: "memory");
    __builtin_amdgcn_s_barrier();
    asm volatile("" ::: "memory");
    COMPUTE(1);

#pragma unroll
    for (int nf = 0; nf < 2; ++nf) {
        const int gc = n0 + wn * 32 + nf * 16 + lr;
        const float br  = bih[gc];
        const float bz  = bih[HDIM + gc];
        const float bnx = bih[2 * HDIM + gc];
        const float bn2 = bun[gc];
#pragma unroll
        for (int mf = 0; mf < 4; ++mf) {
#pragma unroll
            for (int rr = 0; rr < 4; ++rr) {
                const int gr = m0 + wm * 64 + mf * 16 + ls * 4 + rr;
                const float rv = 1.f / (1.f + __expf(-(acc[0][mf][nf][rr] + br)));
                const float zv = 1.f / (1.f + __expf(-(acc[1][mf][nf][rr] + bz)));
                const float nv = tanhf(acc[2][mf][nf][rr] + bnx + rv * (acc[3][mf][nf][rr] + bn2));
                const float hv = hg[(size_t)gr * HDIM + gc];
                out[(size_t)gr * HDIM + gc] = (1.f - zv) * nv + zv * hv;
            }
        }
    }
}

extern "C" void kernel_launch(void* const* d_in, const int* in_sizes, int n_in,
                              void* d_out, int out_size, void* d_ws, size_t ws_size,
                              hipStream_t stream) {
    const float* x   = (const float*)d_in[0];
    const float* h   = (const float*)d_in[1];
    const float* Wih = (const float*)d_in[2];
    const float* bih = (const float*)d_in[3];
    const float* Ur  = (const float*)d_in[4];
    const float* Uz  = (const float*)d_in[5];
    const float* Un  = (const float*)d_in[6];
    const float* bun = (const float*)d_in[7];
    float* out = (float*)d_out;

    unsigned short* wsp  = (unsigned short*)d_ws;
    unsigned short* wihb = wsp;                       // 6 MB
    unsigned short* urb  = wihb + 3 * 1024 * 1024;
    unsigned short* uzb  = urb + 1024 * 1024;
    unsigned short* unb  = uzb + 1024 * 1024;         // 12 MB total
    unsigned short* xff  = unb + 1024 * 1024;         // 16 MB frag-packed x
    unsigned short* hff  = xff + 8 * 1024 * 1024;     // 16 MB frag-packed h

    const bool big = ws_size >= 46137344ull;          // 44 MB

    cvt_w<<<6144, 256, 0, stream>>>(Wih, Ur, Uz, Un, wihb, urb, uzb, unb);

    if (big) {
        pack_xh<<<1024, 256, 0, stream>>>(x, h, xff, hff);
        gru8<<<1024, 512, 0, stream>>>(
            h, xff, hff, wihb, urb, uzb, unb, bih, bun, out);
    } else {
        dim3 grid(HDIM / 64, 8192 / 128);
        gru_fused_fb<<<grid, 256, 0, stream>>>(
            h, x, h, wihb, urb, uzb, unb, bih, bun, out);
    }
}

// Round 6
// 151.456 us; speedup vs baseline: 1.3191x; 1.3191x over previous
//
#include <hip/hip_runtime.h>
#include <hip/hip_bf16.h>
#include <cstdint>

#define HDIM 1024
#define NT 32   // K-tiles of 32

typedef __attribute__((ext_vector_type(8))) __bf16 bf16x8;
typedef __attribute__((ext_vector_type(8))) unsigned short u16x8;
typedef __attribute__((ext_vector_type(4))) float f32x4;

static __device__ __forceinline__ unsigned short f2b(float f) {
    __hip_bfloat16 h = __float2bfloat16(f);
    return __builtin_bit_cast(unsigned short, h);
}

static __device__ __forceinline__ void barrier_fence() {
    asm volatile("" ::: "memory");
    __builtin_amdgcn_s_barrier();
    asm volatile("" ::: "memory");
}

// fp32 -> bf16 pack: weights + x,h (row-major), 44 MB in ws
__global__ void __launch_bounds__(256) cvt_all(
    const float* __restrict__ x, const float* __restrict__ h,
    const float* __restrict__ wih, const float* __restrict__ ur,
    const float* __restrict__ uz, const float* __restrict__ un,
    unsigned short* __restrict__ wb, unsigned short* __restrict__ urb,
    unsigned short* __restrict__ uzb, unsigned short* __restrict__ unb,
    unsigned short* __restrict__ xb, unsigned short* __restrict__ hb) {
    int b = blockIdx.x;
    const float* src; unsigned short* dst; int idx;
    if (b < 3072)       { src = wih; dst = wb;  idx = b; }
    else if (b < 4096)  { src = ur;  dst = urb; idx = b - 3072; }
    else if (b < 5120)  { src = uz;  dst = uzb; idx = b - 4096; }
    else if (b < 6144)  { src = un;  dst = unb; idx = b - 5120; }
    else if (b < 14336) { src = x;   dst = xb;  idx = b - 6144; }
    else                { src = h;   dst = hb;  idx = b - 14336; }
    int i = idx * 256 + threadIdx.x;
    float4 v = ((const float4*)src)[i];
    ushort4 o;
    o.x = f2b(v.x); o.y = f2b(v.y); o.z = f2b(v.z); o.w = f2b(v.w);
    ((ushort4*)dst)[i] = o;
}

// gate map: mi 0(Wr),3(Ur)->acc0 ; 1(Wz),4(Uz)->acc1 ; 2(Wn)->acc2 ; 5(Un)->acc3
template<int MH, int NF>
__device__ __forceinline__ void mm_cluster(f32x4 (&acc)[4][4][2],
        const bf16x8 (&ax)[4], const bf16x8 (&ah)[4], const bf16x8 (&bq)[6]) {
#pragma unroll
    for (int mi = 0; mi < 6; ++mi) {
        const int g = (mi == 0 || mi == 3) ? 0 : (mi == 1 || mi == 4) ? 1 : (mi == 2) ? 2 : 3;
#pragma unroll
        for (int m2 = 0; m2 < 2; ++m2) {
            const int mf = MH * 2 + m2;
            acc[g][mf][NF] = __builtin_amdgcn_mfma_f32_16x16x32_bf16(
                (mi < 3) ? ax[mf] : ah[mf], bq[mi], acc[g][mf][NF], 0, 0, 0);
        }
    }
}

// 8-wave (4M x 2N), BM=256 x BN=64, 4-phase per K-tile, depth-2 prefetch:
//   W double-buffered (staged t+1 at P0), x/h TRIPLE-buffered (staged t+2 at P2),
//   single per-tile counted wait vmcnt(4) at P3 -- never drains mid-loop.
// LDS: wlds[2][24KB] (6 tiles 64x32) + xhlds[3][32KB] (x[0,8192) h[8192,16384)).
// Swizzle (R2-proven, conflict-free): 16B slot s of row r at s ^ ((r>>1)&3).
__global__ void __launch_bounds__(512, 2)
gru4p(const float* __restrict__ hg,
      const unsigned short* __restrict__ xb, const unsigned short* __restrict__ hb,
      const unsigned short* __restrict__ wih,
      const unsigned short* __restrict__ ur,
      const unsigned short* __restrict__ uz,
      const unsigned short* __restrict__ un,
      const float* __restrict__ bih, const float* __restrict__ bun,
      float* __restrict__ out) {
    __shared__ __align__(16) unsigned short wlds[2][12288];
    __shared__ __align__(16) unsigned short xhlds[3][16384];

    const int tid  = threadIdx.x;
    const int lane = tid & 63;
    const int wv   = tid >> 6;     // 0..7
    const int wm   = wv >> 1;      // 0..3 : 64-row quarter
    const int wn   = wv & 1;       // 0..1 : 32-col half
    const int lr   = lane & 15;
    const int ls   = lane >> 4;

    // XCD swizzle: 512 blocks (%8==0 -> simple bijective). 32 same-n-panel
    // blocks run concurrently per XCD -> weights L2-hot after first touch.
    const int bid = blockIdx.x;
    const int swz = (bid & 7) * 64 + (bid >> 3);
    const int m0  = (swz & 31) * 256;
    const int n0  = (swz >> 5) * 64;

    // ---- weight staging ptrs: 3 gload_lds/thread/tile (6 tiles x 256 chunks)
    const unsigned short* wb6[6] = {
        wih + (size_t)n0 * HDIM,
        wih + (size_t)(HDIM + n0) * HDIM,
        wih + (size_t)(2 * HDIM + n0) * HDIM,
        ur  + (size_t)n0 * HDIM,
        uz  + (size_t)n0 * HDIM,
        un  + (size_t)n0 * HDIM
    };
    const unsigned short* pwp[3];
    int wdst[3];
#pragma unroll
    for (int l = 0; l < 3; ++l) {
        const int id = l * 512 + tid;
        const int mi = id >> 8;
        const int c  = id & 255;
        const int r  = c >> 2;
        const int sl = (c & 3) ^ ((c >> 3) & 3);
        pwp[l]  = wb6[mi] + (size_t)r * HDIM + sl * 8;
        wdst[l] = mi * 2048 + (wv & 3) * 512;          // wave-uniform dest
    }
    // ---- x/h staging ptrs: 4 gload_lds/thread/tile (1024 chunks each)
    const unsigned short* pxh[4];
#pragma unroll
    for (int half = 0; half < 2; ++half) {
        const int c  = half * 512 + tid;               // 0..1023
        const int r  = c >> 2;                         // row 0..255
        const int sl = (c & 3) ^ ((c >> 3) & 3);
        pxh[half]     = xb + (size_t)(m0 + r) * HDIM + sl * 8;
        pxh[2 + half] = hb + (size_t)(m0 + r) * HDIM + sl * 8;
    }

    // ---- loop-invariant ds_read offsets (ushort units)
    int aoff[4];
#pragma unroll
    for (int mf = 0; mf < 4; ++mf) {
        const int row = wm * 64 + mf * 16 + lr;
        aoff[mf] = row * 32 + ((ls ^ ((row >> 1) & 3)) << 3);
    }
    const int brow0 = wn * 32 + lr;
    const int brow1 = brow0 + 16;
    const int boff0 = brow0 * 32 + ((ls ^ ((brow0 >> 1) & 3)) << 3);
    const int boff1 = brow1 * 32 + ((ls ^ ((brow1 >> 1) & 3)) << 3);

    f32x4 acc[4][4][2];
#pragma unroll
    for (int g = 0; g < 4; ++g)
#pragma unroll
        for (int mf = 0; mf < 4; ++mf)
#pragma unroll
            for (int nf = 0; nf < 2; ++nf)
                acc[g][mf][nf] = f32x4{0.f, 0.f, 0.f, 0.f};

    auto STAGE_W = [&](unsigned short* nb) {
#pragma unroll
        for (int l = 0; l < 3; ++l) {
            __builtin_amdgcn_global_load_lds(
                (const __attribute__((address_space(1))) void*)pwp[l],
                (__attribute__((address_space(3))) void*)(nb + wdst[l]), 16, 0, 0);
            pwp[l] += 32;
        }
    };
    auto STAGE_XH = [&](unsigned short* nb) {
#pragma unroll
        for (int half = 0; half < 2; ++half) {
            __builtin_amdgcn_global_load_lds(
                (const __attribute__((address_space(1))) void*)pxh[half],
                (__attribute__((address_space(3))) void*)(nb + half * 4096 + wv * 512),
                16, 0, 0);
            pxh[half] += 32;
            __builtin_amdgcn_global_load_lds(
                (const __attribute__((address_space(1))) void*)pxh[2 + half],
                (__attribute__((address_space(3))) void*)(nb + 8192 + half * 4096 + wv * 512),
                16, 0, 0);
            pxh[2 + half] += 32;
        }
    };

    // prologue: XH(0), XH(1), W(0) -> one-time full drain
    STAGE_XH(&xhlds[0][0]);
    STAGE_XH(&xhlds[1][0]);
    STAGE_W(&wlds[0][0]);
    asm volatile("s_waitcnt vmcnt(0)" ::: "memory");
    barrier_fence();

    int xi = 0;
#pragma unroll 1
    for (int t = 0; t < NT; ++t) {
        const unsigned short* xc = &xhlds[xi][0];
        const unsigned short* wc = &wlds[t & 1][0];
        bf16x8 ax[4], ah[4], b0[6], b1[6];

        // ---- P0: read A(mh0) 4 + B(nf0) 6 | stage W(t+1)
        ax[0] = *(const bf16x8*)(xc + aoff[0]);
        ax[1] = *(const bf16x8*)(xc + aoff[1]);
        ah[0] = *(const bf16x8*)(xc + 8192 + aoff[0]);
        ah[1] = *(const bf16x8*)(xc + 8192 + aoff[1]);
#pragma unroll
        for (int mi = 0; mi < 6; ++mi)
            b0[mi] = *(const bf16x8*)(wc + mi * 2048 + boff0);
        if (t + 1 < NT) STAGE_W(&wlds[(t + 1) & 1][0]);
        barrier_fence();
        asm volatile("s_waitcnt lgkmcnt(0)" ::: "memory");
        __builtin_amdgcn_sched_barrier(0);
        __builtin_amdgcn_s_setprio(1);
        mm_cluster<0, 0>(acc, ax, ah, b0);
        __builtin_amdgcn_s_setprio(0);
        barrier_fence();

        // ---- P1: read A(mh1) 4
        ax[2] = *(const bf16x8*)(xc + aoff[2]);
        ax[3] = *(const bf16x8*)(xc + aoff[3]);
        ah[2] = *(const bf16x8*)(xc + 8192 + aoff[2]);
        ah[3] = *(const bf16x8*)(xc + 8192 + aoff[3]);
        barrier_fence();
        asm volatile("s_waitcnt lgkmcnt(0)" ::: "memory");
        __builtin_amdgcn_sched_barrier(0);
        __builtin_amdgcn_s_setprio(1);
        mm_cluster<1, 0>(acc, ax, ah, b0);
        __builtin_amdgcn_s_setprio(0);
        barrier_fence();

        // ---- P2: read B(nf1) 6 | stage XH(t+2) (depth-2 prefetch)
#pragma unroll
        for (int mi = 0; mi < 6; ++mi)
            b1[mi] = *(const bf16x8*)(wc + mi * 2048 + boff1);
        if (t + 2 < NT) {
            int ni = xi + 2; if (ni >= 3) ni -= 3;
            STAGE_XH(&xhlds[ni][0]);
        }
        barrier_fence();
        asm volatile("s_waitcnt lgkmcnt(0)" ::: "memory");
        __builtin_amdgcn_sched_barrier(0);
        __builtin_amdgcn_s_setprio(1);
        mm_cluster<0, 1>(acc, ax, ah, b1);
        __builtin_amdgcn_s_setprio(0);
        barrier_fence();

        // ---- P3: pure MFMA; counted wait (leaves the 4 XH(t+2) loads in flight)
        __builtin_amdgcn_s_setprio(1);
        mm_cluster<1, 1>(acc, ax, ah, b1);
        __builtin_amdgcn_s_setprio(0);
        if (t + 2 < NT) { asm volatile("s_waitcnt vmcnt(4)" ::: "memory"); }
        else            { asm volatile("s_waitcnt vmcnt(0)" ::: "memory"); }
        barrier_fence();

        if (++xi == 3) xi = 0;
    }

    // epilogue (C/D: col=lane&15, row=(lane>>4)*4+reg)
#pragma unroll
    for (int nf = 0; nf < 2; ++nf) {
        const int gc = n0 + wn * 32 + nf * 16 + lr;
        const float br  = bih[gc];
        const float bz  = bih[HDIM + gc];
        const float bnx = bih[2 * HDIM + gc];
        const float bn2 = bun[gc];
#pragma unroll
        for (int mf = 0; mf < 4; ++mf) {
#pragma unroll
            for (int rr = 0; rr < 4; ++rr) {
                const int gr = m0 + wm * 64 + mf * 16 + ls * 4 + rr;
                const float rv = 1.f / (1.f + __expf(-(acc[0][mf][nf][rr] + br)));
                const float zv = 1.f / (1.f + __expf(-(acc[1][mf][nf][rr] + bz)));
                const float nv = tanhf(acc[2][mf][nf][rr] + bnx + rv * (acc[3][mf][nf][rr] + bn2));
                const float hv = hg[(size_t)gr * HDIM + gc];
                out[(size_t)gr * HDIM + gc] = (1.f - zv) * nv + zv * hv;
            }
        }
    }
}

// ---------- fallback (ws too small): R2's proven 4-wave fp32-staging kernel ----------
__global__ void __launch_bounds__(256, 2)
gru_fused_fb(const float* __restrict__ hg,
             const float* __restrict__ xg32, const float* __restrict__ hg32,
             const unsigned short* __restrict__ wih,
             const unsigned short* __restrict__ ur,
             const unsigned short* __restrict__ uz,
             const unsigned short* __restrict__ un,
             const float* __restrict__ bih, const float* __restrict__ bun,
             float* __restrict__ out) {
    __shared__ __align__(16) unsigned short smem[2][20480];
    const int tid  = threadIdx.x;
    const int lane = tid & 63;
    const int wv   = tid >> 6;
    const int wm   = wv >> 1;
    const int wn   = wv & 1;
    const int lr   = lane & 15;
    const int ls   = lane >> 4;
    const int m0   = blockIdx.y * 128;
    const int n0   = blockIdx.x * 64;

    const unsigned short* wb6[6] = {
        wih + (size_t)n0 * HDIM, wih + (size_t)(HDIM + n0) * HDIM,
        wih + (size_t)(2 * HDIM + n0) * HDIM, ur + (size_t)n0 * HDIM,
        uz + (size_t)n0 * HDIM, un + (size_t)n0 * HDIM
    };
    const int wr  = tid >> 2;
    const int wsl = (tid & 3) ^ ((tid >> 3) & 3);

    f32x4 acc[4][4][2];
#pragma unroll
    for (int g = 0; g < 4; ++g)
#pragma unroll
        for (int mf = 0; mf < 4; ++mf)
#pragma unroll
            for (int nf = 0; nf < 2; ++nf)
                acc[g][mf][nf] = f32x4{0.f, 0.f, 0.f, 0.f};

    auto STAGE = [&](int bufi, int kt) {
        const int k0 = kt * 32;
        unsigned short* sb = &smem[bufi][0];
        float4 fx[2][2], fh[2][2];
#pragma unroll
        for (int half = 0; half < 2; ++half) {
            const int c2 = half * 256 + tid;
            const int r2 = c2 >> 2;
            const int sl = c2 & 3;
            const float* gx = xg32 + (size_t)(m0 + r2) * HDIM + k0 + sl * 8;
            const float* gh = hg32 + (size_t)(m0 + r2) * HDIM + k0 + sl * 8;
            fx[half][0] = ((const float4*)gx)[0];
            fx[half][1] = ((const float4*)gx)[1];
            fh[half][0] = ((const float4*)gh)[0];
            fh[half][1] = ((const float4*)gh)[1];
        }
#pragma unroll
        for (int mi = 0; mi < 6; ++mi) {
            const unsigned short* g = wb6[mi] + (size_t)wr * HDIM + k0 + wsl * 8;
            __builtin_amdgcn_global_load_lds(
                (const __attribute__((address_space(1))) void*)g,
                (__attribute__((address_space(3))) void*)(sb + 8192 + mi * 2048 + wv * 512),
                16, 0, 0);
        }
#pragma unroll
        for (int half = 0; half < 2; ++half) {
            const int c2 = half * 256 + tid;
            const int r2 = c2 >> 2;
            const int sp = (c2 & 3) ^ ((c2 >> 3) & 3);
            u16x8 px, ph;
#pragma unroll
            for (int q = 0; q < 4; ++q) {
                px[q]     = f2b(fx[half][0][q]);
                px[q + 4] = f2b(fx[half][1][q]);
                ph[q]     = f2b(fh[half][0][q]);
                ph[q + 4] = f2b(fh[half][1][q]);
            }
            *(u16x8*)(sb + r2 * 32 + sp * 8)        = px;
            *(u16x8*)(sb + 4096 + r2 * 32 + sp * 8) = ph;
        }
    };
    auto COMPUTE = [&](int bufi) {
        const unsigned short* sb = &smem[bufi][0];
        const int sel = (lr >> 1) & 3;
        const int fo  = (ls ^ sel) << 3;
        bf16x8 ax[4], ah[4];
#pragma unroll
        for (int mf = 0; mf < 4; ++mf) {
            const int row = wm * 64 + mf * 16 + lr;
            ax[mf] = *(const bf16x8*)(sb + row * 32 + fo);
            ah[mf] = *(const bf16x8*)(sb + 4096 + row * 32 + fo);
        }
#pragma unroll
        for (int mi = 0; mi < 6; ++mi) {
            const unsigned short* wt = sb + 8192 + mi * 2048;
            bf16x8 b0 = *(const bf16x8*)(wt + (wn * 32 + lr) * 32 + fo);
            bf16x8 b1 = *(const bf16x8*)(wt + (wn * 32 + 16 + lr) * 32 + fo);
            const int g = (mi == 0 || mi == 3) ? 0 : (mi == 1 || mi == 4) ? 1 : (mi == 2) ? 2 : 3;
            const bf16x8* a = (mi < 3) ? ax : ah;
#pragma unroll
            for (int mf = 0; mf < 4; ++mf) {
                acc[g][mf][0] = __builtin_amdgcn_mfma_f32_16x16x32_bf16(a[mf], b0, acc[g][mf][0], 0, 0, 0);
                acc[g][mf][1] = __builtin_amdgcn_mfma_f32_16x16x32_bf16(a[mf], b1, acc[g][mf][1], 0, 0, 0);
            }
        }
    };
    auto WAITN = [&]() { asm volatile("s_waitcnt vmcnt(6) lgkmcnt(0)" ::: "memory"); };

    STAGE(0, 0);
#pragma unroll 1
    for (int kt = 0; kt < NT - 2; kt += 2) {
        STAGE(1, kt + 1); WAITN(); barrier_fence();
        COMPUTE(0);       barrier_fence();
        STAGE(0, kt + 2); WAITN(); barrier_fence();
        COMPUTE(1);       barrier_fence();
    }
    STAGE(1, NT - 1); WAITN(); barrier_fence();
    COMPUTE(0);       barrier_fence();
    asm volatile("s_waitcnt vmcnt(0) lgkmcnt(0)" ::: "memory");
    __builtin_amdgcn_s_barrier();
    asm volatile("" ::: "memory");
    COMPUTE(1);

#pragma unroll
    for (int nf = 0; nf < 2; ++nf) {
        const int gc = n0 + wn * 32 + nf * 16 + lr;
        const float br  = bih[gc];
        const float bz  = bih[HDIM + gc];
        const float bnx = bih[2 * HDIM + gc];
        const float bn2 = bun[gc];
#pragma unroll
        for (int mf = 0; mf < 4; ++mf) {
#pragma unroll
            for (int rr = 0; rr < 4; ++rr) {
                const int gr = m0 + wm * 64 + mf * 16 + ls * 4 + rr;
                const float rv = 1.f / (1.f + __expf(-(acc[0][mf][nf][rr] + br)));
                const float zv = 1.f / (1.f + __expf(-(acc[1][mf][nf][rr] + bz)));
                const float nv = tanhf(acc[2][mf][nf][rr] + bnx + rv * (acc[3][mf][nf][rr] + bn2));
                const float hv = hg[(size_t)gr * HDIM + gc];
                out[(size_t)gr * HDIM + gc] = (1.f - zv) * nv + zv * hv;
            }
        }
    }
}

extern "C" void kernel_launch(void* const* d_in, const int* in_sizes, int n_in,
                              void* d_out, int out_size, void* d_ws, size_t ws_size,
                              hipStream_t stream) {
    const float* x   = (const float*)d_in[0];
    const float* h   = (const float*)d_in[1];
    const float* Wih = (const float*)d_in[2];
    const float* bih = (const float*)d_in[3];
    const float* Ur  = (const float*)d_in[4];
    const float* Uz  = (const float*)d_in[5];
    const float* Un  = (const float*)d_in[6];
    const float* bun = (const float*)d_in[7];
    float* out = (float*)d_out;

    unsigned short* wsp  = (unsigned short*)d_ws;
    unsigned short* wihb = wsp;
    unsigned short* urb  = wihb + 3 * 1024 * 1024;
    unsigned short* uzb  = urb + 1024 * 1024;
    unsigned short* unb  = uzb + 1024 * 1024;
    unsigned short* xbb  = unb + 1024 * 1024;
    unsigned short* hbb  = xbb + 8 * 1024 * 1024;

    const bool big = ws_size >= 46137344ull;  // 44 MB

    cvt_all<<<big ? 22528 : 6144, 256, 0, stream>>>(
        x, h, Wih, Ur, Uz, Un, wihb, urb, uzb, unb, xbb, hbb);

    if (big) {
        gru4p<<<512, 512, 0, stream>>>(
            h, xbb, hbb, wihb, urb, uzb, unb, bih, bun, out);
    } else {
        dim3 grid(HDIM / 64, 8192 / 128);
        gru_fused_fb<<<grid, 256, 0, stream>>>(
            h, x, h, wihb, urb, uzb, unb, bih, bun, out);
    }
}